// Round 16
// baseline (130.846 us; speedup 1.0000x reference)
//
#include <hip/hip_runtime.h>
#include <hip/hip_bf16.h>
#include <cstdint>
#include <cstddef>

typedef __bf16 bf16;
typedef __attribute__((ext_vector_type(8))) __bf16 bf16x8;
typedef __attribute__((ext_vector_type(4))) __bf16 bf16x4;
typedef __attribute__((ext_vector_type(4))) float f32x4;
typedef __attribute__((ext_vector_type(4))) short s16x4;

#define B_ 2
#define S_ 2048
#define D_ 1024
#define H_ 16
#define DK_ 64
#define NROWS (B_*S_)   // 4096
#define NBIAS 4095      // rel in [-2047,2047]
#define LDQ 3072        // fused QKV row stride
#define LOG2E 1.44269504f

__device__ __forceinline__ void async16(void* lds, const void* g) {
  __builtin_amdgcn_global_load_lds(
      (const __attribute__((address_space(1))) void*)g,
      (__attribute__((address_space(3))) void*)lds, 16, 0, 0);
}

__device__ __forceinline__ f32x4 mfma16(bf16x8 a, bf16x8 b, f32x4 c) {
  return __builtin_amdgcn_mfma_f32_16x16x32_bf16(a, b, c, 0, 0, 0);
}

__device__ __forceinline__ s16x4 bc4(bf16x4 x) {
  union { bf16x4 b; s16x4 s; } u; u.b = x; return u.s;
}

// K=16 MFMA: pairs with the swapped-QK^T C-layout (verified R3-R14).
__device__ __forceinline__ f32x4 mfma16k(bf16x4 a, bf16x4 b, f32x4 c) {
  return __builtin_amdgcn_mfma_f32_16x16x16bf16_1k(bc4(a), bc4(b), c, 0, 0, 0);
}

// Hazard-safe single-instruction HW exp2 (R8 lesson: raw asm corrupts).
__device__ __forceinline__ float exp2_hw(float x) {
  return __builtin_amdgcn_exp2f(x);
}

// -------------------------------------------------------- fused prep kernel
__global__ void prep_kernel(const float* __restrict__ X,
                            const float* __restrict__ Wq, const float* __restrict__ Wk,
                            const float* __restrict__ Wv, const float* __restrict__ Wo,
                            const float* __restrict__ rel_emb,
                            bf16* __restrict__ Xb, bf16* __restrict__ oqkv,
                            bf16* __restrict__ oo, float* __restrict__ tab) {
  const int bid = blockIdx.x;
  const int tid = threadIdx.x;
  if (bid < 4096) {
    int i = bid * 256 + tid;
    float4 v = ((const float4*)X)[i];
    bf16x4 o;
    o[0] = (bf16)v.x; o[1] = (bf16)v.y; o[2] = (bf16)v.z; o[3] = (bf16)v.w;
    ((bf16x4*)Xb)[i] = o;
  } else if (bid < 8192) {
    int widx = bid - 4096;
    int y = widx >> 10;
    const float* src = (y == 0) ? Wq : (y == 1) ? Wk : (y == 2) ? Wv : Wo;
    bf16* dst = (y < 3) ? (oqkv + (size_t)y * D_ * D_) : oo;
    int i = (widx & 1023) * 256 + tid;
    float4 v = ((const float4*)src)[i];
    bf16x4 o;
    o[0] = (bf16)v.x; o[1] = (bf16)v.y; o[2] = (bf16)v.z; o[3] = (bf16)v.w;
    ((bf16x4*)dst)[i] = o;
  } else {
    int idx = (bid - 8192) * 256 + tid;
    if (idx >= H_ * NBIAS) return;
    int h = idx / NBIAS;
    int p = idx - h * NBIAS;
    int rel = p - 2047;          // k - q  (mem - ctx)
    int n = -rel;                // per reference: n = -relative_position
    int ret = 0;
    if (n < 0) { ret = 16; n = -n; }
    int bucket;
    if (n < 8) {
      bucket = ret + n;
    } else {
      double v = log((double)n / 8.0) / log(16.0) * 8.0;
      int vi = 8 + (int)v;
      if (vi > 15) vi = 15;
      bucket = ret + vi;
    }
    tab[idx] = rel_emb[bucket * H_ + h] * LOG2E;
  }
}

// ---------------------------------------------------------------- GEMM (bt)
// C[M][N] = alpha * A[M][K] @ B[N][K]^T ; alpha = (n0 < colThr) ? a0 : a1
// Tile (MF*32) x 128 x BK64; 4 waves (2x2); wave (MF*16) x 64.
// VT_EP: blocks with n0 >= vThr write their tile TRANSPOSED to VT.
template<int OUT_BF16, int MF, int VT_EP>
__global__ __launch_bounds__(256, 3)
void gemm_bt(const bf16* __restrict__ A, const bf16* __restrict__ Bw,
             void* __restrict__ C, bf16* __restrict__ VT, int vThr,
             int M, int N, int K, int colThr, float a0, float a1) {
  __shared__ bf16 smem[MF * 32 * 64 + 128 * 64];
  bf16* As = smem;
  bf16* Bs = smem + MF * 32 * 64;
  const int tid = threadIdx.x;
  const int lane = tid & 63;
  const int w = tid >> 6;
  const int wr = w >> 1, wc = w & 1;
  const int l15 = lane & 15, lhi = lane >> 4;
  const int m0 = blockIdx.y * (MF * 32), n0 = blockIdx.x * 128;
  const float alpha = (n0 < colThr) ? a0 : a1;

  f32x4 acc[MF][4] = {};

  const int urow = tid >> 3;                 // 0..31
  const int uswz = (tid & 7) ^ (urow & 7);   // pre-swizzled global 16B unit
  const bf16* ga = A  + (size_t)(m0 + urow) * K + uswz * 8;
  const bf16* gb = Bw + (size_t)(n0 + urow) * K + uswz * 8;

  for (int kt = 0; kt < K; kt += 64) {
#pragma unroll
    for (int rnd = 0; rnd < MF; ++rnd)
      async16(As + tid * 8 + rnd * 2048, ga + kt + (size_t)(rnd * 32) * K);
#pragma unroll
    for (int rnd = 0; rnd < 4; ++rnd)
      async16(Bs + tid * 8 + rnd * 2048, gb + kt + (size_t)(rnd * 32) * K);
    __syncthreads();

#pragma unroll
    for (int kc = 0; kc < 2; ++kc) {
      bf16x8 af[MF], bfr[4];
#pragma unroll
      for (int m = 0; m < MF; ++m) {
        int row = wr * (MF * 16) + m * 16 + l15;
        int off = (row * 64 + kc * 32 + lhi * 8) ^ ((row & 7) << 3);
        af[m] = *(const bf16x8*)&As[off];
      }
#pragma unroll
      for (int n = 0; n < 4; ++n) {
        int row = wc * 64 + n * 16 + l15;
        int off = (row * 64 + kc * 32 + lhi * 8) ^ ((row & 7) << 3);
        bfr[n] = *(const bf16x8*)&Bs[off];
      }
      __builtin_amdgcn_s_setprio(1);
#pragma unroll
      for (int m = 0; m < MF; ++m)
#pragma unroll
        for (int n = 0; n < 4; ++n)
          acc[m][n] = mfma16(af[m], bfr[n], acc[m][n]);
      __builtin_amdgcn_s_setprio(0);
    }
    __syncthreads();
  }

  if (VT_EP && n0 >= vThr) {
    bf16* T = smem;  // 128*128 bf16 = 32 KB
#pragma unroll
    for (int m = 0; m < MF; ++m)
#pragma unroll
      for (int n = 0; n < 4; ++n)
#pragma unroll
        for (int r = 0; r < 4; ++r) {
          int rl = wr * (MF * 16) + m * 16 + lhi * 4 + r;  // s-local
          int cl = wc * 64 + n * 16 + l15;                 // d-local
          T[cl * 128 + (rl ^ ((cl & 7) << 3))] = (bf16)(acc[m][n][r] * alpha);
        }
    __syncthreads();
    const int bb = m0 >> 11, s0l = m0 & 2047, d0 = n0 - vThr;
    const int dr = tid >> 1, sh = tid & 1;
    bf16* dst = VT + ((size_t)(bb * 1024 + d0 + dr)) * 2048 + s0l + sh * 64;
    const bf16* src = T + dr * 128;
#pragma unroll
    for (int i = 0; i < 8; ++i) {
      int sb = sh * 8 + i;
      *(bf16x8*)(dst + i * 8) = *(const bf16x8*)(src + ((sb ^ (dr & 7)) * 8));
    }
    return;
  }

#pragma unroll
  for (int m = 0; m < MF; ++m)
#pragma unroll
    for (int n = 0; n < 4; ++n)
#pragma unroll
      for (int r = 0; r < 4; ++r) {
        int row = m0 + wr * (MF * 16) + m * 16 + lhi * 4 + r;
        int col = n0 + wc * 64 + n * 16 + l15;
        float v = acc[m][n][r] * alpha;
        if (OUT_BF16) ((bf16*)C)[(size_t)row * N + col] = (bf16)v;
        else          ((float*)C)[(size_t)row * N + col] = v;
      }
}

// ---------------------------------------------------------------- attention
// R16 = R15 minus the compile slip: KV-split ACROSS BLOCKS.  grid 1024 =
// (qt,half)x(bh); each block does QBLK=128 q-rows x 1024 KV (16 steps) ->
// 4 blocks/CU, 4 waves/SIMD, with R11's halved LDS traffic.  No-max softmax
// => halves merge by addition: block writes UNNORMALIZED bf16 partial-O
// (half0->Xb, half1->QKVb V-cols) + per-row l (f32); tiny merge kernel
// combines.  Body = R11 (ring-2, __syncthreads); launch_bounds(256,4).
__global__ __launch_bounds__(256, 4)
void attn_fwd(const bf16* __restrict__ QKV, const bf16* __restrict__ VTg_,
              const float* __restrict__ biasTab, const float* __restrict__ rel_emb,
              bf16* __restrict__ Op0, bf16* __restrict__ Op1,
              float* __restrict__ Lws) {
  __shared__ bf16 Ks[2][64 * 64];    // [kpos][d]  swizzled via pre-swizzled source
  __shared__ bf16 VTs[2][64 * 64];   // [d][kpos]  swizzled via pre-swizzled source
  __shared__ float bias_s[512];      // near window: k-q in [-255,255]
  const int tid = threadIdx.x;
  const int lane = tid & 63, w = tid >> 6;
  const int l15 = lane & 15, lhi = lane >> 4;
  const int wg = blockIdx.x;
  const int bh = wg & 31;            // fastest -> head's blocks share XCD L2
  const int rest = wg >> 5;          // 0..31
  const int qt = rest >> 1, h3 = rest & 1;
  const int b = bh >> 4, h = bh & 15;
  const int q0 = qt * 128;
  const int kvbase = h3 << 10;       // 0 or 1024

  // near-window bias: LDS i = (k-q)+255 ; global idx = (k-q)+2047 = i+1792
  for (int i = tid; i < 511; i += 256)
    bias_s[i] = biasTab[h * NBIAS + 1792 + i];

  // saturated-bucket constants: k-q <= -91 -> bucket15 ; k-q >= 91 -> bucket31
  const float cL = rel_emb[15 * H_ + h] * LOG2E;
  const float cR = rel_emb[31 * H_ + h] * LOG2E;

  // Q fragments (scaled 0.125*log2e in QKV gemm): B-operand of swapped QK^T
  bf16x8 qa[2][2];
  {
    const bf16* Qbase = QKV + (size_t)(b * S_ + q0 + w * 32) * LDQ + h * DK_;
#pragma unroll
    for (int qf = 0; qf < 2; ++qf)
#pragma unroll
      for (int c = 0; c < 2; ++c)
        qa[qf][c] = *(const bf16x8*)(Qbase + (size_t)(qf * 16 + l15) * LDQ + c * 32 + lhi * 8);
  }

  // hoisted LDS byte offsets (buf0; buf1 adds literal 8192)
  int koff[8];
#pragma unroll
  for (int kf = 0; kf < 4; ++kf)
#pragma unroll
    for (int c = 0; c < 2; ++c) {
      int krow = kf * 16 + l15;
      koff[kf * 2 + c] = ((krow * 64 + c * 32 + lhi * 8) ^ ((krow & 7) << 3)) * 2;
    }
  int voff[16];
#pragma unroll
  for (int df = 0; df < 4; ++df)
#pragma unroll
    for (int kf = 0; kf < 4; ++kf)
      voff[df * 4 + kf] =
          (((df * 16 + l15) * 64 + kf * 16 + lhi * 4) * 2) ^ ((l15 & 7) << 4);

  float lpart[2] = {0.f, 0.f};
  f32x4 oacc[2][4] = {};

  const int urow = tid >> 3;                  // 0..31
  const int uswz = (tid & 7) ^ (urow & 7);    // 16B-unit swizzle (64-elem rows)
  const bf16* gk = QKV  + (size_t)(b * S_ + kvbase) * LDQ + 1024 + h * DK_
                        + (size_t)urow * LDQ + uswz * 8;
  const bf16* gv = VTg_ + (size_t)(b * 1024 + h * DK_) * 2048 + kvbase
                        + (size_t)urow * 2048 + uswz * 8;

  // ---- prologue: stage step 0 into buf0
  async16(&Ks[0][tid * 8],         gk);
  async16(&Ks[0][tid * 8 + 2048],  gk + 32 * LDQ);
  async16(&VTs[0][tid * 8],        gv);
  async16(&VTs[0][tid * 8 + 2048], gv + 32 * 2048);
  gk += 64 * LDQ;  gv += 64;
  __syncthreads();

#define TILE_BODY(CUR, KT, DO_PF)                                              \
  do {                                                                         \
    if (DO_PF) {                                                               \
      async16(&Ks[(CUR) ^ 1][tid * 8],         gk);                            \
      async16(&Ks[(CUR) ^ 1][tid * 8 + 2048],  gk + 32 * LDQ);                 \
      async16(&VTs[(CUR) ^ 1][tid * 8],        gv);                            \
      async16(&VTs[(CUR) ^ 1][tid * 8 + 2048], gv + 32 * 2048);                \
      gk += 64 * LDQ;  gv += 64;                                               \
    }                                                                          \
    const int dk0 = kvbase + (KT) - q0;                                        \
    f32x4 st[2][4];                                                            \
    if (dk0 >= -128 && dk0 <= 192) {                                           \
      const int bb0 = dk0 + lhi * 4 - w * 32 - l15 + 255;                      \
      _Pragma("unroll")                                                        \
      for (int qf = 0; qf < 2; ++qf)                                           \
        _Pragma("unroll")                                                      \
        for (int kf = 0; kf < 4; ++kf)                                         \
          _Pragma("unroll")                                                    \
          for (int r = 0; r < 4; ++r)                                          \
            st[qf][kf][r] = bias_s[bb0 + (kf - qf) * 16 + r];                  \
    } else {                                                                   \
      const float cq = (dk0 > 0) ? cR : cL;                                    \
      _Pragma("unroll")                                                        \
      for (int qf = 0; qf < 2; ++qf)                                           \
        _Pragma("unroll")                                                      \
        for (int kf = 0; kf < 4; ++kf)                                         \
          _Pragma("unroll")                                                    \
          for (int r = 0; r < 4; ++r)                                          \
            st[qf][kf][r] = cq;                                                \
    }                                                                          \
    _Pragma("unroll")                                                          \
    for (int kf = 0; kf < 4; ++kf) {                                           \
      _Pragma("unroll")                                                        \
      for (int c = 0; c < 2; ++c) {                                            \
        bf16x8 kb = *(const bf16x8*)((const char*)&Ks[CUR][0] +                \
                                     koff[kf * 2 + c]);                        \
        st[0][kf] = mfma16(kb, qa[0][c], st[0][kf]);                           \
        st[1][kf] = mfma16(kb, qa[1][c], st[1][kf]);                           \
      }                                                                        \
    }                                                                          \
    bf16x4 pa[2][4];                                                           \
    _Pragma("unroll")                                                          \
    for (int qf = 0; qf < 2; ++qf) {                                           \
      float rs = 0.f;                                                          \
      _Pragma("unroll")                                                        \
      for (int kf = 0; kf < 4; ++kf)                                           \
        _Pragma("unroll")                                                      \
        for (int r = 0; r < 4; ++r) {                                          \
          float p = exp2_hw(st[qf][kf][r]);                                    \
          rs += p;                                                             \
          pa[qf][kf][r] = (bf16)p;                                             \
        }                                                                      \
      lpart[qf] += rs;                                                         \
    }                                                                          \
    _Pragma("unroll")                                                          \
    for (int df = 0; df < 4; ++df) {                                           \
      bf16x4 vb[4];                                                            \
      _Pragma("unroll")                                                        \
      for (int kf = 0; kf < 4; ++kf)                                           \
        vb[kf] = *(const bf16x4*)((const char*)&VTs[CUR][0] +                  \
                                  voff[df * 4 + kf]);                          \
      _Pragma("unroll")                                                        \
      for (int qf = 0; qf < 2; ++qf)                                           \
        _Pragma("unroll")                                                      \
        for (int kf = 0; kf < 4; ++kf)                                         \
          oacc[qf][df] = mfma16k(pa[qf][kf], vb[kf], oacc[qf][df]);            \
    }                                                                          \
    __syncthreads();                                                           \
  } while (0)

  for (int tt = 0; tt < 8; ++tt) {
    const int ktbase = tt * 128;
    TILE_BODY(0, ktbase, true);
    TILE_BODY(1, ktbase + 64, tt < 7);
  }
#undef TILE_BODY

  // ---- epilogue: write UNNORMALIZED partial O (bf16) + per-row l (f32)
  bf16* Op = h3 ? Op1 : Op0;
  const int ostride = h3 ? LDQ : D_;     // Op1 lives in QKVb V-cols
  const int obase = h3 ? 2048 : 0;
#pragma unroll
  for (int qf = 0; qf < 2; ++qf) {
    float lr0 = lpart[qf];
    lr0 += __shfl_xor(lr0, 16);
    lr0 += __shfl_xor(lr0, 32);
#pragma unroll
    for (int r = 0; r < 4; ++r) {
      float lr = __shfl(lr0, lhi * 4 + r);
      int row = b * S_ + q0 + w * 32 + qf * 16 + lhi * 4 + r;
      if (l15 == 0) Lws[(h3 * H_ + h) * NROWS + row] = lr;
#pragma unroll
      for (int df = 0; df < 4; ++df)
        Op[(size_t)row * ostride + obase + h * DK_ + df * 16 + l15] =
            (bf16)oacc[qf][df][r];
    }
  }
}

// ------------------------------------------------------------- merge halves
// Out[row][col] = (O0[row][col] + O1[row][col]) / (l0[h][row] + l1[h][row])
__global__ __launch_bounds__(256)
void merge_kernel(const bf16* __restrict__ O0, const bf16* __restrict__ O1,
                  const float* __restrict__ L, bf16* __restrict__ Out) {
  int idx = blockIdx.x * 256 + threadIdx.x;   // 524288
  int row = idx >> 7;
  int col = (idx & 127) * 8;
  int h = col >> 6;
  float inv = 1.0f / (L[h * NROWS + row] + L[(H_ + h) * NROWS + row]);
  bf16x8 a = *(const bf16x8*)(O0 + (size_t)row * D_ + col);
  bf16x8 c = *(const bf16x8*)(O1 + (size_t)row * LDQ + 2048 + col);
  bf16x8 o;
#pragma unroll
  for (int j = 0; j < 8; ++j)
    o[j] = (bf16)(((float)a[j] + (float)c[j]) * inv);
  *(bf16x8*)(Out + (size_t)row * D_ + col) = o;
}

// ---------------------------------------------------------------- launch
extern "C" void kernel_launch(void* const* d_in, const int* in_sizes, int n_in,
                              void* d_out, int out_size, void* d_ws, size_t ws_size,
                              hipStream_t stream) {
  const float* X   = (const float*)d_in[0];
  const float* Wq  = (const float*)d_in[1];
  const float* Wk  = (const float*)d_in[2];
  const float* Wv  = (const float*)d_in[3];
  const float* Wo  = (const float*)d_in[4];
  const float* rel = (const float*)d_in[5];
  float* out = (float*)d_out;
  char* ws = (char*)d_ws;
  const size_t MB = 1u << 20;
  bf16* Xb    = (bf16*)(ws + 0 * MB);    // 8 MB  X-bf16; then attn partial-O half0
  bf16* Wqkvb = (bf16*)(ws + 8 * MB);    // 6 MB  [3072][1024]
  bf16* Wob   = (bf16*)(ws + 14 * MB);   // 2 MB
  bf16* QKVb  = (bf16*)(ws + 16 * MB);   // 24 MB [4096][3072]; V-cols = partial-O half1
  bf16* VTb   = (bf16*)(ws + 40 * MB);   // 8 MB  [2048][2048] V^T; then merged O
  float* biasTab = (float*)(ws + 48 * MB);  // 16*4095*4 B
  float* Lws  = (float*)(ws + 49 * MB);  // 2*16*4096 f32 = 512 KB

  // fused prep: X cvt + 4 weight cvts + bias table, one launch
  prep_kernel<<<8448, 256, 0, stream>>>(X, Wq, Wk, Wv, Wo, rel,
                                        Xb, Wqkvb, Wob, biasTab);

  // fused QKV projection; V cols written TRANSPOSED to VTb by epilogue
  gemm_bt<1, 4, 1><<<dim3(24, 32), 256, 0, stream>>>(Xb, Wqkvb, QKVb,
      VTb, /*vThr=*/2048,
      NROWS, 3 * D_, D_, /*colThr=*/1024, /*aQ=*/0.125f * LOG2E, /*a1=*/1.0f);

  // attention: 1024 blocks = (qt,half) x bh; partials into Xb / QKVb-Vcols
  attn_fwd<<<1024, 256, 0, stream>>>(QKVb, VTb, biasTab, rel,
                                     Xb, QKVb, Lws);

  // merge halves -> VTb (reused as [4096][1024] merged attn output)
  merge_kernel<<<2048, 256, 0, stream>>>(Xb, QKVb, Lws, VTb);

  // out projection reads merged O from VTb
  gemm_bt<0, 2, 0><<<dim3(8, 64), 256, 0, stream>>>(VTb, Wob, out,
      nullptr, 1 << 30,
      NROWS, D_, D_, /*colThr=*/0, 1.0f, 1.0f);
}

// Round 17
// 115.598 us; speedup vs baseline: 1.1319x; 1.1319x over previous
//
#include <hip/hip_runtime.h>
#include <hip/hip_bf16.h>
#include <cstdint>
#include <cstddef>

typedef __bf16 bf16;
typedef __attribute__((ext_vector_type(8))) __bf16 bf16x8;
typedef __attribute__((ext_vector_type(4))) __bf16 bf16x4;
typedef __attribute__((ext_vector_type(4))) float f32x4;
typedef __attribute__((ext_vector_type(4))) short s16x4;

#define B_ 2
#define S_ 2048
#define D_ 1024
#define H_ 16
#define DK_ 64
#define NROWS (B_*S_)   // 4096
#define NBIAS 4095      // rel in [-2047,2047]
#define LDQ 3072        // fused QKV row stride
#define LOG2E 1.44269504f

__device__ __forceinline__ void async16(void* lds, const void* g) {
  __builtin_amdgcn_global_load_lds(
      (const __attribute__((address_space(1))) void*)g,
      (__attribute__((address_space(3))) void*)lds, 16, 0, 0);
}

__device__ __forceinline__ f32x4 mfma16(bf16x8 a, bf16x8 b, f32x4 c) {
  return __builtin_amdgcn_mfma_f32_16x16x32_bf16(a, b, c, 0, 0, 0);
}

__device__ __forceinline__ s16x4 bc4(bf16x4 x) {
  union { bf16x4 b; s16x4 s; } u; u.b = x; return u.s;
}

// K=16 MFMA: pairs with the swapped-QK^T C-layout (verified R3-R16).
__device__ __forceinline__ f32x4 mfma16k(bf16x4 a, bf16x4 b, f32x4 c) {
  return __builtin_amdgcn_mfma_f32_16x16x16bf16_1k(bc4(a), bc4(b), c, 0, 0, 0);
}

// Hazard-safe single-instruction HW exp2 (R8 lesson: raw asm corrupts).
__device__ __forceinline__ float exp2_hw(float x) {
  return __builtin_amdgcn_exp2f(x);
}

// -------------------------------------------------------- fused prep kernel
__global__ void prep_kernel(const float* __restrict__ X,
                            const float* __restrict__ Wq, const float* __restrict__ Wk,
                            const float* __restrict__ Wv, const float* __restrict__ Wo,
                            const float* __restrict__ rel_emb,
                            bf16* __restrict__ Xb, bf16* __restrict__ oqkv,
                            bf16* __restrict__ oo, float* __restrict__ tab) {
  const int bid = blockIdx.x;
  const int tid = threadIdx.x;
  if (bid < 4096) {
    int i = bid * 256 + tid;
    float4 v = ((const float4*)X)[i];
    bf16x4 o;
    o[0] = (bf16)v.x; o[1] = (bf16)v.y; o[2] = (bf16)v.z; o[3] = (bf16)v.w;
    ((bf16x4*)Xb)[i] = o;
  } else if (bid < 8192) {
    int widx = bid - 4096;
    int y = widx >> 10;
    const float* src = (y == 0) ? Wq : (y == 1) ? Wk : (y == 2) ? Wv : Wo;
    bf16* dst = (y < 3) ? (oqkv + (size_t)y * D_ * D_) : oo;
    int i = (widx & 1023) * 256 + tid;
    float4 v = ((const float4*)src)[i];
    bf16x4 o;
    o[0] = (bf16)v.x; o[1] = (bf16)v.y; o[2] = (bf16)v.z; o[3] = (bf16)v.w;
    ((bf16x4*)dst)[i] = o;
  } else {
    int idx = (bid - 8192) * 256 + tid;
    if (idx >= H_ * NBIAS) return;
    int h = idx / NBIAS;
    int p = idx - h * NBIAS;
    int rel = p - 2047;          // k - q  (mem - ctx)
    int n = -rel;                // per reference: n = -relative_position
    int ret = 0;
    if (n < 0) { ret = 16; n = -n; }
    int bucket;
    if (n < 8) {
      bucket = ret + n;
    } else {
      double v = log((double)n / 8.0) / log(16.0) * 8.0;
      int vi = 8 + (int)v;
      if (vi > 15) vi = 15;
      bucket = ret + vi;
    }
    tab[idx] = rel_emb[bucket * H_ + h] * LOG2E;
  }
}

// ---------------------------------------------------------------- GEMM (bt)
// C[M][N] = alpha * A[M][K] @ B[N][K]^T ; alpha = (n0 < colThr) ? a0 : a1
// Tile (MF*32) x 128 x BK64; 4 waves (2x2); wave (MF*16) x 64.
// VT_EP: blocks with n0 >= vThr write their tile TRANSPOSED to VT.
template<int OUT_BF16, int MF, int VT_EP>
__global__ __launch_bounds__(256, 3)
void gemm_bt(const bf16* __restrict__ A, const bf16* __restrict__ Bw,
             void* __restrict__ C, bf16* __restrict__ VT, int vThr,
             int M, int N, int K, int colThr, float a0, float a1) {
  __shared__ bf16 smem[MF * 32 * 64 + 128 * 64];
  bf16* As = smem;
  bf16* Bs = smem + MF * 32 * 64;
  const int tid = threadIdx.x;
  const int lane = tid & 63;
  const int w = tid >> 6;
  const int wr = w >> 1, wc = w & 1;
  const int l15 = lane & 15, lhi = lane >> 4;
  const int m0 = blockIdx.y * (MF * 32), n0 = blockIdx.x * 128;
  const float alpha = (n0 < colThr) ? a0 : a1;

  f32x4 acc[MF][4] = {};

  const int urow = tid >> 3;                 // 0..31
  const int uswz = (tid & 7) ^ (urow & 7);   // pre-swizzled global 16B unit
  const bf16* ga = A  + (size_t)(m0 + urow) * K + uswz * 8;
  const bf16* gb = Bw + (size_t)(n0 + urow) * K + uswz * 8;

  for (int kt = 0; kt < K; kt += 64) {
#pragma unroll
    for (int rnd = 0; rnd < MF; ++rnd)
      async16(As + tid * 8 + rnd * 2048, ga + kt + (size_t)(rnd * 32) * K);
#pragma unroll
    for (int rnd = 0; rnd < 4; ++rnd)
      async16(Bs + tid * 8 + rnd * 2048, gb + kt + (size_t)(rnd * 32) * K);
    __syncthreads();

#pragma unroll
    for (int kc = 0; kc < 2; ++kc) {
      bf16x8 af[MF], bfr[4];
#pragma unroll
      for (int m = 0; m < MF; ++m) {
        int row = wr * (MF * 16) + m * 16 + l15;
        int off = (row * 64 + kc * 32 + lhi * 8) ^ ((row & 7) << 3);
        af[m] = *(const bf16x8*)&As[off];
      }
#pragma unroll
      for (int n = 0; n < 4; ++n) {
        int row = wc * 64 + n * 16 + l15;
        int off = (row * 64 + kc * 32 + lhi * 8) ^ ((row & 7) << 3);
        bfr[n] = *(const bf16x8*)&Bs[off];
      }
      __builtin_amdgcn_s_setprio(1);
#pragma unroll
      for (int m = 0; m < MF; ++m)
#pragma unroll
        for (int n = 0; n < 4; ++n)
          acc[m][n] = mfma16(af[m], bfr[n], acc[m][n]);
      __builtin_amdgcn_s_setprio(0);
    }
    __syncthreads();
  }

  if (VT_EP && n0 >= vThr) {
    bf16* T = smem;  // 128*128 bf16 = 32 KB
#pragma unroll
    for (int m = 0; m < MF; ++m)
#pragma unroll
      for (int n = 0; n < 4; ++n)
#pragma unroll
        for (int r = 0; r < 4; ++r) {
          int rl = wr * (MF * 16) + m * 16 + lhi * 4 + r;  // s-local
          int cl = wc * 64 + n * 16 + l15;                 // d-local
          T[cl * 128 + (rl ^ ((cl & 7) << 3))] = (bf16)(acc[m][n][r] * alpha);
        }
    __syncthreads();
    const int bb = m0 >> 11, s0l = m0 & 2047, d0 = n0 - vThr;
    const int dr = tid >> 1, sh = tid & 1;
    bf16* dst = VT + ((size_t)(bb * 1024 + d0 + dr)) * 2048 + s0l + sh * 64;
    const bf16* src = T + dr * 128;
#pragma unroll
    for (int i = 0; i < 8; ++i) {
      int sb = sh * 8 + i;
      *(bf16x8*)(dst + i * 8) = *(const bf16x8*)(src + ((sb ^ (dr & 7)) * 8));
    }
    return;
  }

#pragma unroll
  for (int m = 0; m < MF; ++m)
#pragma unroll
    for (int n = 0; n < 4; ++n)
#pragma unroll
      for (int r = 0; r < 4; ++r) {
        int row = m0 + wr * (MF * 16) + m * 16 + lhi * 4 + r;
        int col = n0 + wc * 64 + n * 16 + l15;
        float v = acc[m][n][r] * alpha;
        if (OUT_BF16) ((bf16*)C)[(size_t)row * N + col] = (bf16)v;
        else          ((float*)C)[(size_t)row * N + col] = v;
      }
}

// ---------------------------------------------------------------- attention
// R17 = R14 pipeline (no merge) with KVBLK=128: 16 steps instead of 32 ->
// half the barriers/vmcnt-drains, 2x the per-body ILP window.  QBLK=128,
// 4 waves x 32 q-rows; ring-2 dbuf; LDS 66KB -> 2 blocks/CU (unchanged).
// No-max exp2 softmax; bias (or saturated const) as QK^T MFMA C-in.
// Near tiles: dk0 in {-128,0,128}; far tiles saturate (|rel|>=129>=91).
__global__ __launch_bounds__(256, 2)
void attn_fwd(const bf16* __restrict__ QKV, const bf16* __restrict__ VTg_,
              const float* __restrict__ biasTab, const float* __restrict__ rel_emb,
              bf16* __restrict__ Og) {
  __shared__ bf16 Ks[2][128 * 64];   // [kpos][d]  swizzled via pre-swizzled source
  __shared__ bf16 VTs[2][64 * 128];  // [d][kpos]  swizzled via pre-swizzled source
  __shared__ float bias_s[512];      // near window: k-q in [-255,255]
  const int tid = threadIdx.x;
  const int lane = tid & 63, w = tid >> 6;
  const int l15 = lane & 15, lhi = lane >> 4;
  const int wg = blockIdx.x;
  const int bh = wg & 31, qt = wg >> 5;
  const int b = bh >> 4, h = bh & 15;
  const int q0 = qt * 128;

  // near-window bias: LDS i = (k-q)+255 ; global idx = (k-q)+2047 = i+1792
  for (int i = tid; i < 511; i += 256)
    bias_s[i] = biasTab[h * NBIAS + 1792 + i];

  // saturated-bucket constants: k-q <= -91 -> bucket15 ; k-q >= 91 -> bucket31
  const float cL = rel_emb[15 * H_ + h] * LOG2E;
  const float cR = rel_emb[31 * H_ + h] * LOG2E;

  // Q fragments (scaled 0.125*log2e in QKV gemm): B-operand of swapped QK^T
  bf16x8 qa[2][2];
  {
    const bf16* Qbase = QKV + (size_t)(b * S_ + q0 + w * 32) * LDQ + h * DK_;
#pragma unroll
    for (int qf = 0; qf < 2; ++qf)
#pragma unroll
      for (int c = 0; c < 2; ++c)
        qa[qf][c] = *(const bf16x8*)(Qbase + (size_t)(qf * 16 + l15) * LDQ + c * 32 + lhi * 8);
  }

  // hoisted LDS offsets.  K tile [128][64]: krow = kf*16+l15 (kf 0..7).
  int koff[16];
#pragma unroll
  for (int kf = 0; kf < 8; ++kf)
#pragma unroll
    for (int c = 0; c < 2; ++c) {
      int krow = kf * 16 + l15;
      koff[kf * 2 + c] = ((krow * 64 + c * 32 + lhi * 8) ^ ((krow & 7) << 3)) * 2;
    }
  // V tile [64][128], staged with unit-swizzle (unit ^ (row&7)) on 256B rows.
  // read 8B at (row=df*16+l15, col=kf*16+lhi*4):
  //   byte = row*256 + (((kf*2+(lhi>>1)) ^ (l15&7))<<4) + (lhi&1)*8
  int voff[8];
#pragma unroll
  for (int kf = 0; kf < 8; ++kf)
    voff[kf] = l15 * 256 + ((((kf * 2 + (lhi >> 1)) ^ (l15 & 7))) << 4) + (lhi & 1) * 8;

  float lpart[2] = {0.f, 0.f};
  f32x4 oacc[2][4] = {};

  const int urow = tid >> 3;                  // 0..31 (K staging, 64-elem rows)
  const int uswz = (tid & 7) ^ (urow & 7);
  const int vrow = tid >> 4;                  // 0..15 (V staging, 128-elem rows)
  const int vswz = (tid & 15) ^ (vrow & 7);
  const bf16* gk = QKV  + (size_t)(b * S_) * LDQ + 1024 + h * DK_
                        + (size_t)urow * LDQ + uswz * 8;
  const bf16* gv = VTg_ + (size_t)(b * 1024 + h * DK_ + vrow) * 2048 + vswz * 8;

  // ---- prologue: stage step 0 into buf0 (K: 4x32 rows; V: 4x16 rows)
#pragma unroll
  for (int s2 = 0; s2 < 4; ++s2) {
    async16(&Ks[0][tid * 8 + s2 * 2048],  gk + (size_t)(s2 * 32) * LDQ);
    async16(&VTs[0][tid * 8 + s2 * 2048], gv + (size_t)(s2 * 16) * 2048);
  }
  gk += 128 * LDQ;  gv += 128;
  __syncthreads();

#define TILE_BODY(CUR, KT, DO_PF)                                              \
  do {                                                                         \
    if (DO_PF) {                                                               \
      _Pragma("unroll")                                                        \
      for (int s2 = 0; s2 < 4; ++s2) {                                         \
        async16(&Ks[(CUR) ^ 1][tid * 8 + s2 * 2048],                           \
                gk + (size_t)(s2 * 32) * LDQ);                                 \
        async16(&VTs[(CUR) ^ 1][tid * 8 + s2 * 2048],                          \
                gv + (size_t)(s2 * 16) * 2048);                                \
      }                                                                        \
      gk += 128 * LDQ;  gv += 128;                                             \
    }                                                                          \
    const int dk0 = (KT) - q0;                                                 \
    f32x4 st[2][8];                                                            \
    if (dk0 >= -128 && dk0 <= 128) {                                           \
      const int bb0 = dk0 + lhi * 4 - w * 32 - l15 + 255;                      \
      _Pragma("unroll")                                                        \
      for (int qf = 0; qf < 2; ++qf)                                           \
        _Pragma("unroll")                                                      \
        for (int kf = 0; kf < 8; ++kf)                                         \
          _Pragma("unroll")                                                    \
          for (int r = 0; r < 4; ++r)                                          \
            st[qf][kf][r] = bias_s[bb0 + (kf - qf) * 16 + r];                  \
    } else {                                                                   \
      const float cq = (dk0 > 0) ? cR : cL;                                    \
      _Pragma("unroll")                                                        \
      for (int qf = 0; qf < 2; ++qf)                                           \
        _Pragma("unroll")                                                      \
        for (int kf = 0; kf < 8; ++kf)                                         \
          _Pragma("unroll")                                                    \
          for (int r = 0; r < 4; ++r)                                          \
            st[qf][kf][r] = cq;                                                \
    }                                                                          \
    _Pragma("unroll")                                                          \
    for (int kf = 0; kf < 8; ++kf) {                                           \
      _Pragma("unroll")                                                        \
      for (int c = 0; c < 2; ++c) {                                            \
        bf16x8 kb = *(const bf16x8*)((const char*)&Ks[CUR][0] +                \
                                     koff[kf * 2 + c]);                        \
        st[0][kf] = mfma16(kb, qa[0][c], st[0][kf]);                           \
        st[1][kf] = mfma16(kb, qa[1][c], st[1][kf]);                           \
      }                                                                        \
    }                                                                          \
    bf16x4 pa[2][8];                                                           \
    _Pragma("unroll")                                                          \
    for (int qf = 0; qf < 2; ++qf) {                                           \
      float rs = 0.f;                                                          \
      _Pragma("unroll")                                                        \
      for (int kf = 0; kf < 8; ++kf)                                           \
        _Pragma("unroll")                                                      \
        for (int r = 0; r < 4; ++r) {                                          \
          float p = exp2_hw(st[qf][kf][r]);                                    \
          rs += p;                                                             \
          pa[qf][kf][r] = (bf16)p;                                             \
        }                                                                      \
      lpart[qf] += rs;                                                         \
    }                                                                          \
    _Pragma("unroll")                                                          \
    for (int df = 0; df < 4; ++df) {                                           \
      bf16x4 vb[8];                                                            \
      _Pragma("unroll")                                                        \
      for (int kf = 0; kf < 8; ++kf)                                           \
        vb[kf] = *(const bf16x4*)((const char*)&VTs[CUR][0] +                  \
                                  (df * 4096 + voff[kf]));                     \
      _Pragma("unroll")                                                        \
      for (int qf = 0; qf < 2; ++qf)                                           \
        _Pragma("unroll")                                                      \
        for (int kf = 0; kf < 8; ++kf)                                         \
          oacc[qf][df] = mfma16k(pa[qf][kf], vb[kf], oacc[qf][df]);            \
    }                                                                          \
    __syncthreads();                                                           \
  } while (0)

  for (int tt = 0; tt < 8; ++tt) {
    const int ktbase = tt * 256;
    TILE_BODY(0, ktbase, true);
    TILE_BODY(1, ktbase + 128, tt < 7);
  }
#undef TILE_BODY

  // epilogue: reduce l across lane groups, normalize, store bf16
#pragma unroll
  for (int qf = 0; qf < 2; ++qf) {
    float lr0 = lpart[qf];
    lr0 += __shfl_xor(lr0, 16);
    lr0 += __shfl_xor(lr0, 32);
#pragma unroll
    for (int r = 0; r < 4; ++r) {
      float lr = __shfl(lr0, lhi * 4 + r);
      float inv = 1.0f / lr;
#pragma unroll
      for (int df = 0; df < 4; ++df) {
        int row = b * S_ + q0 + w * 32 + qf * 16 + lhi * 4 + r;
        int col = h * DK_ + df * 16 + l15;
        Og[(size_t)row * D_ + col] = (bf16)(oacc[qf][df][r] * inv);
      }
    }
  }
}

// ---------------------------------------------------------------- launch
extern "C" void kernel_launch(void* const* d_in, const int* in_sizes, int n_in,
                              void* d_out, int out_size, void* d_ws, size_t ws_size,
                              hipStream_t stream) {
  const float* X   = (const float*)d_in[0];
  const float* Wq  = (const float*)d_in[1];
  const float* Wk  = (const float*)d_in[2];
  const float* Wv  = (const float*)d_in[3];
  const float* Wo  = (const float*)d_in[4];
  const float* rel = (const float*)d_in[5];
  float* out = (float*)d_out;
  char* ws = (char*)d_ws;
  const size_t MB = 1u << 20;
  bf16* Xb    = (bf16*)(ws + 0 * MB);    // 8 MB  (also reused as attn output Ob)
  bf16* Wqkvb = (bf16*)(ws + 8 * MB);    // 6 MB  [3072][1024]
  bf16* Wob   = (bf16*)(ws + 14 * MB);   // 2 MB
  bf16* QKVb  = (bf16*)(ws + 16 * MB);   // 24 MB [4096][3072] (V cols unused)
  bf16* VTb   = (bf16*)(ws + 40 * MB);   // 8 MB  [2048][2048]
  float* biasTab = (float*)(ws + 48 * MB);  // 16*4095*4 B

  // fused prep: X cvt + 4 weight cvts + bias table, one launch
  prep_kernel<<<8448, 256, 0, stream>>>(X, Wq, Wk, Wv, Wo, rel,
                                        Xb, Wqkvb, Wob, biasTab);

  // fused QKV projection; V cols written TRANSPOSED to VTb by epilogue
  gemm_bt<1, 4, 1><<<dim3(24, 32), 256, 0, stream>>>(Xb, Wqkvb, QKVb,
      VTb, /*vThr=*/2048,
      NROWS, 3 * D_, D_, /*colThr=*/1024, /*aQ=*/0.125f * LOG2E, /*a1=*/1.0f);

  attn_fwd<<<512, 256, 0, stream>>>(QKVb, VTb, biasTab, rel, Xb /*Ob*/);

  // out projection: 64x128 tiles -> 512 blocks
  gemm_bt<0, 2, 0><<<dim3(8, 64), 256, 0, stream>>>(Xb, Wob, out,
      nullptr, 1 << 30,
      NROWS, D_, D_, /*colThr=*/0, 1.0f, 1.0f);
}

// Round 18
// 114.852 us; speedup vs baseline: 1.1393x; 1.0065x over previous
//
#include <hip/hip_runtime.h>
#include <hip/hip_bf16.h>
#include <cstdint>
#include <cstddef>

typedef __bf16 bf16;
typedef __attribute__((ext_vector_type(8))) __bf16 bf16x8;
typedef __attribute__((ext_vector_type(4))) __bf16 bf16x4;
typedef __attribute__((ext_vector_type(4))) float f32x4;
typedef __attribute__((ext_vector_type(4))) short s16x4;

#define B_ 2
#define S_ 2048
#define D_ 1024
#define H_ 16
#define DK_ 64
#define NROWS (B_*S_)   // 4096
#define NBIAS 4095      // rel in [-2047,2047]
#define LDQ 3072        // fused QKV row stride
#define LOG2E 1.44269504f

__device__ __forceinline__ void async16(void* lds, const void* g) {
  __builtin_amdgcn_global_load_lds(
      (const __attribute__((address_space(1))) void*)g,
      (__attribute__((address_space(3))) void*)lds, 16, 0, 0);
}

__device__ __forceinline__ f32x4 mfma16(bf16x8 a, bf16x8 b, f32x4 c) {
  return __builtin_amdgcn_mfma_f32_16x16x32_bf16(a, b, c, 0, 0, 0);
}

__device__ __forceinline__ s16x4 bc4(bf16x4 x) {
  union { bf16x4 b; s16x4 s; } u; u.b = x; return u.s;
}

// K=16 MFMA: pairs with the swapped-QK^T C-layout (verified R3-R17).
__device__ __forceinline__ f32x4 mfma16k(bf16x4 a, bf16x4 b, f32x4 c) {
  return __builtin_amdgcn_mfma_f32_16x16x16bf16_1k(bc4(a), bc4(b), c, 0, 0, 0);
}

// Hazard-safe single-instruction HW exp2 (R8 lesson: raw asm corrupts).
__device__ __forceinline__ float exp2_hw(float x) {
  return __builtin_amdgcn_exp2f(x);
}

// -------------------------------------------------------- fused prep kernel
__global__ void prep_kernel(const float* __restrict__ X,
                            const float* __restrict__ Wq, const float* __restrict__ Wk,
                            const float* __restrict__ Wv, const float* __restrict__ Wo,
                            const float* __restrict__ rel_emb,
                            bf16* __restrict__ Xb, bf16* __restrict__ oqkv,
                            bf16* __restrict__ oo, float* __restrict__ tab) {
  const int bid = blockIdx.x;
  const int tid = threadIdx.x;
  if (bid < 4096) {
    int i = bid * 256 + tid;
    float4 v = ((const float4*)X)[i];
    bf16x4 o;
    o[0] = (bf16)v.x; o[1] = (bf16)v.y; o[2] = (bf16)v.z; o[3] = (bf16)v.w;
    ((bf16x4*)Xb)[i] = o;
  } else if (bid < 8192) {
    int widx = bid - 4096;
    int y = widx >> 10;
    const float* src = (y == 0) ? Wq : (y == 1) ? Wk : (y == 2) ? Wv : Wo;
    bf16* dst = (y < 3) ? (oqkv + (size_t)y * D_ * D_) : oo;
    int i = (widx & 1023) * 256 + tid;
    float4 v = ((const float4*)src)[i];
    bf16x4 o;
    o[0] = (bf16)v.x; o[1] = (bf16)v.y; o[2] = (bf16)v.z; o[3] = (bf16)v.w;
    ((bf16x4*)dst)[i] = o;
  } else {
    int idx = (bid - 8192) * 256 + tid;
    if (idx >= H_ * NBIAS) return;
    int h = idx / NBIAS;
    int p = idx - h * NBIAS;
    int rel = p - 2047;          // k - q  (mem - ctx)
    int n = -rel;                // per reference: n = -relative_position
    int ret = 0;
    if (n < 0) { ret = 16; n = -n; }
    int bucket;
    if (n < 8) {
      bucket = ret + n;
    } else {
      double v = log((double)n / 8.0) / log(16.0) * 8.0;
      int vi = 8 + (int)v;
      if (vi > 15) vi = 15;
      bucket = ret + vi;
    }
    tab[idx] = rel_emb[bucket * H_ + h] * LOG2E;
  }
}

// ---------------------------------------------------------------- GEMM (bt)
// C[M][N] = alpha * A[M][K] @ B[N][K]^T ; alpha = (n0 < colThr) ? a0 : a1
// Tile (MF*32) x 128 x BK64; 4 waves (2x2); wave (MF*16) x 64.
// VT_EP: blocks with n0 >= vThr write their tile TRANSPOSED to VT.
template<int OUT_BF16, int MF, int VT_EP>
__global__ __launch_bounds__(256, 3)
void gemm_bt(const bf16* __restrict__ A, const bf16* __restrict__ Bw,
             void* __restrict__ C, bf16* __restrict__ VT, int vThr,
             int M, int N, int K, int colThr, float a0, float a1) {
  __shared__ bf16 smem[MF * 32 * 64 + 128 * 64];
  bf16* As = smem;
  bf16* Bs = smem + MF * 32 * 64;
  const int tid = threadIdx.x;
  const int lane = tid & 63;
  const int w = tid >> 6;
  const int wr = w >> 1, wc = w & 1;
  const int l15 = lane & 15, lhi = lane >> 4;
  const int m0 = blockIdx.y * (MF * 32), n0 = blockIdx.x * 128;
  const float alpha = (n0 < colThr) ? a0 : a1;

  f32x4 acc[MF][4] = {};

  const int urow = tid >> 3;                 // 0..31
  const int uswz = (tid & 7) ^ (urow & 7);   // pre-swizzled global 16B unit
  const bf16* ga = A  + (size_t)(m0 + urow) * K + uswz * 8;
  const bf16* gb = Bw + (size_t)(n0 + urow) * K + uswz * 8;

  for (int kt = 0; kt < K; kt += 64) {
#pragma unroll
    for (int rnd = 0; rnd < MF; ++rnd)
      async16(As + tid * 8 + rnd * 2048, ga + kt + (size_t)(rnd * 32) * K);
#pragma unroll
    for (int rnd = 0; rnd < 4; ++rnd)
      async16(Bs + tid * 8 + rnd * 2048, gb + kt + (size_t)(rnd * 32) * K);
    __syncthreads();

#pragma unroll
    for (int kc = 0; kc < 2; ++kc) {
      bf16x8 af[MF], bfr[4];
#pragma unroll
      for (int m = 0; m < MF; ++m) {
        int row = wr * (MF * 16) + m * 16 + l15;
        int off = (row * 64 + kc * 32 + lhi * 8) ^ ((row & 7) << 3);
        af[m] = *(const bf16x8*)&As[off];
      }
#pragma unroll
      for (int n = 0; n < 4; ++n) {
        int row = wc * 64 + n * 16 + l15;
        int off = (row * 64 + kc * 32 + lhi * 8) ^ ((row & 7) << 3);
        bfr[n] = *(const bf16x8*)&Bs[off];
      }
      __builtin_amdgcn_s_setprio(1);
#pragma unroll
      for (int m = 0; m < MF; ++m)
#pragma unroll
        for (int n = 0; n < 4; ++n)
          acc[m][n] = mfma16(af[m], bfr[n], acc[m][n]);
      __builtin_amdgcn_s_setprio(0);
    }
    __syncthreads();
  }

  if (VT_EP && n0 >= vThr) {
    bf16* T = smem;  // 128*128 bf16 = 32 KB
#pragma unroll
    for (int m = 0; m < MF; ++m)
#pragma unroll
      for (int n = 0; n < 4; ++n)
#pragma unroll
        for (int r = 0; r < 4; ++r) {
          int rl = wr * (MF * 16) + m * 16 + lhi * 4 + r;  // s-local
          int cl = wc * 64 + n * 16 + l15;                 // d-local
          T[cl * 128 + (rl ^ ((cl & 7) << 3))] = (bf16)(acc[m][n][r] * alpha);
        }
    __syncthreads();
    const int bb = m0 >> 11, s0l = m0 & 2047, d0 = n0 - vThr;
    const int dr = tid >> 1, sh = tid & 1;
    bf16* dst = VT + ((size_t)(bb * 1024 + d0 + dr)) * 2048 + s0l + sh * 64;
    const bf16* src = T + dr * 128;
#pragma unroll
    for (int i = 0; i < 8; ++i) {
      int sb = sh * 8 + i;
      *(bf16x8*)(dst + i * 8) = *(const bf16x8*)(src + ((sb ^ (dr & 7)) * 8));
    }
    return;
  }

#pragma unroll
  for (int m = 0; m < MF; ++m)
#pragma unroll
    for (int n = 0; n < 4; ++n)
#pragma unroll
      for (int r = 0; r < 4; ++r) {
        int row = m0 + wr * (MF * 16) + m * 16 + lhi * 4 + r;
        int col = n0 + wc * 64 + n * 16 + l15;
        float v = acc[m][n][r] * alpha;
        if (OUT_BF16) ((bf16*)C)[(size_t)row * N + col] = (bf16)v;
        else          ((float*)C)[(size_t)row * N + col] = v;
      }
}

// ---------------------------------------------------------------- attention
// R18 = best-measured attn (R10 config, 60.3 us twice): QBLK=64, KVBLK=64,
// dbuf ring-2, 4 blocks/CU (grid 1024 = qt(32) x bh(32)), hoisted LDS
// offsets, bias (or saturated const) as QK^T MFMA C-in, no-max exp2 softmax
// via __builtin_amdgcn_exp2f, k-loop unrolled 2x (literal buffer bases).
__global__ __launch_bounds__(256, 4)
void attn_fwd(const bf16* __restrict__ QKV, const bf16* __restrict__ VTg_,
              const float* __restrict__ biasTab, const float* __restrict__ rel_emb,
              bf16* __restrict__ Og) {
  __shared__ bf16 Ks[2][64 * 64];    // [kpos][d]  swizzled via pre-swizzled source
  __shared__ bf16 VTs[2][64 * 64];   // [d][kpos]  swizzled via pre-swizzled source
  __shared__ float bias_s[512];      // near window: k-q in [-256,255]
  const int tid = threadIdx.x;
  const int lane = tid & 63, w = tid >> 6;
  const int l15 = lane & 15, lhi = lane >> 4;
  const int wg = blockIdx.x;
  const int bh = wg & 31, qt = wg >> 5;
  const int b = bh >> 4, h = bh & 15;
  const int q0 = qt * 64;

  // near-window bias: LDS i = (k-q)+256 ; global idx = (k-q)+2047 = i+1791
  for (int i = tid; i < 512; i += 256)
    bias_s[i] = biasTab[h * NBIAS + 1791 + i];

  // saturated-bucket constants: k-q <= -91 -> bucket15 ; k-q >= 91 -> bucket31
  const float cL = rel_emb[15 * H_ + h] * LOG2E;
  const float cR = rel_emb[31 * H_ + h] * LOG2E;

  // Q fragments (scaled 0.125*log2e in QKV gemm): B-operand of swapped QK^T
  bf16x8 qa[2];
  {
    const bf16* Qbase = QKV + (size_t)(b * S_ + q0 + w * 16) * LDQ + h * DK_;
#pragma unroll
    for (int c = 0; c < 2; ++c)
      qa[c] = *(const bf16x8*)(Qbase + (size_t)l15 * LDQ + c * 32 + lhi * 8);
  }

  // ---- hoisted LDS byte offsets (buf0; buf1 adds constant 8192)
  int koff[8];   // [kf*2+c]  K-fragment ds_read_b128
#pragma unroll
  for (int kf = 0; kf < 4; ++kf)
#pragma unroll
    for (int c = 0; c < 2; ++c) {
      int krow = kf * 16 + l15;
      koff[kf * 2 + c] = ((krow * 64 + c * 32 + lhi * 8) ^ ((krow & 7) << 3)) * 2;
    }
  int voff[16];  // [df*4+kf]  V-fragment ds_read_b64
#pragma unroll
  for (int df = 0; df < 4; ++df)
#pragma unroll
    for (int kf = 0; kf < 4; ++kf)
      voff[df * 4 + kf] =
          (((df * 16 + l15) * 64 + kf * 16 + lhi * 4) * 2) ^ ((l15 & 7) << 4);

  float lpart = 0.f;                // per-lane partial sum (reduced in epilogue)
  f32x4 oacc[4] = {};

  const int urow = tid >> 3;                  // 0..31
  const int uswz = (tid & 7) ^ (urow & 7);    // 16B-unit swizzle (64-elem rows)
  const bf16* gk = QKV  + (size_t)(b * S_) * LDQ + 1024 + h * DK_
                        + (size_t)urow * LDQ + uswz * 8;
  const bf16* gv = VTg_ + (size_t)(b * 1024 + h * DK_) * 2048
                        + (size_t)urow * 2048 + uswz * 8;

  // ---- prologue: stage tile 0 into buf0, advance pointers to tile 1
  async16(&Ks[0][tid * 8],         gk);
  async16(&Ks[0][tid * 8 + 2048],  gk + 32 * LDQ);
  async16(&VTs[0][tid * 8],        gv);
  async16(&VTs[0][tid * 8 + 2048], gv + 32 * 2048);
  gk += 64 * LDQ;
  gv += 64;
  __syncthreads();

#define TILE_BODY(CUR, KT, DO_PF)                                              \
  do {                                                                         \
    if (DO_PF) {                                                               \
      async16(&Ks[(CUR) ^ 1][tid * 8],         gk);                            \
      async16(&Ks[(CUR) ^ 1][tid * 8 + 2048],  gk + 32 * LDQ);                 \
      async16(&VTs[(CUR) ^ 1][tid * 8],        gv);                            \
      async16(&VTs[(CUR) ^ 1][tid * 8 + 2048], gv + 32 * 2048);                \
      gk += 64 * LDQ;                                                          \
      gv += 64;                                                                \
    }                                                                          \
    const int dk0 = (KT) - q0;                                                 \
    f32x4 st[4];                                                               \
    if (dk0 >= -128 && dk0 <= 128) {                                           \
      const int bb0 = dk0 + lhi * 4 - (w * 16 + l15) + 256;                    \
      _Pragma("unroll")                                                        \
      for (int kf = 0; kf < 4; ++kf)                                           \
        _Pragma("unroll")                                                      \
        for (int r = 0; r < 4; ++r)                                            \
          st[kf][r] = bias_s[bb0 + kf * 16 + r];                               \
    } else {                                                                   \
      const float cq = (dk0 > 0) ? cR : cL;                                    \
      _Pragma("unroll")                                                        \
      for (int kf = 0; kf < 4; ++kf)                                           \
        _Pragma("unroll")                                                      \
        for (int r = 0; r < 4; ++r)                                            \
          st[kf][r] = cq;                                                      \
    }                                                                          \
    _Pragma("unroll")                                                          \
    for (int kf = 0; kf < 4; ++kf) {                                           \
      _Pragma("unroll")                                                        \
      for (int c = 0; c < 2; ++c) {                                            \
        bf16x8 kb = *(const bf16x8*)((const char*)&Ks[CUR][0] +                \
                                     koff[kf * 2 + c]);                        \
        st[kf] = mfma16(kb, qa[c], st[kf]);                                    \
      }                                                                        \
    }                                                                          \
    bf16x4 pa[4];                                                              \
    float rs = 0.f;                                                            \
    _Pragma("unroll")                                                          \
    for (int kf = 0; kf < 4; ++kf)                                             \
      _Pragma("unroll")                                                        \
      for (int r = 0; r < 4; ++r) {                                            \
        float p = exp2_hw(st[kf][r]);                                          \
        rs += p;                                                               \
        pa[kf][r] = (bf16)p;                                                   \
      }                                                                        \
    lpart += rs;                                                               \
    _Pragma("unroll")                                                          \
    for (int df = 0; df < 4; ++df) {                                           \
      bf16x4 vb[4];                                                            \
      _Pragma("unroll")                                                        \
      for (int kf = 0; kf < 4; ++kf)                                           \
        vb[kf] = *(const bf16x4*)((const char*)&VTs[CUR][0] +                  \
                                  voff[df * 4 + kf]);                          \
      _Pragma("unroll")                                                        \
      for (int kf = 0; kf < 4; ++kf)                                           \
        oacc[df] = mfma16k(pa[kf], vb[kf], oacc[df]);                          \
    }                                                                          \
    __syncthreads();                                                           \
  } while (0)

  for (int tt = 0; tt < 16; ++tt) {
    const int ktbase = tt * 128;
    TILE_BODY(0, ktbase, true);
    TILE_BODY(1, ktbase + 64, tt < 15);
  }
#undef TILE_BODY

  // epilogue: reduce l across lane groups, normalize, store bf16
  float lr0 = lpart;
  lr0 += __shfl_xor(lr0, 16);
  lr0 += __shfl_xor(lr0, 32);
#pragma unroll
  for (int r = 0; r < 4; ++r) {
    float lr = __shfl(lr0, lhi * 4 + r);
    float inv = 1.0f / lr;
#pragma unroll
    for (int df = 0; df < 4; ++df) {
      int row = b * S_ + q0 + w * 16 + lhi * 4 + r;
      int col = h * DK_ + df * 16 + l15;
      Og[(size_t)row * D_ + col] = (bf16)(oacc[df][r] * inv);
    }
  }
}

// ---------------------------------------------------------------- launch
extern "C" void kernel_launch(void* const* d_in, const int* in_sizes, int n_in,
                              void* d_out, int out_size, void* d_ws, size_t ws_size,
                              hipStream_t stream) {
  const float* X   = (const float*)d_in[0];
  const float* Wq  = (const float*)d_in[1];
  const float* Wk  = (const float*)d_in[2];
  const float* Wv  = (const float*)d_in[3];
  const float* Wo  = (const float*)d_in[4];
  const float* rel = (const float*)d_in[5];
  float* out = (float*)d_out;
  char* ws = (char*)d_ws;
  const size_t MB = 1u << 20;
  bf16* Xb    = (bf16*)(ws + 0 * MB);    // 8 MB  (also reused as attn output Ob)
  bf16* Wqkvb = (bf16*)(ws + 8 * MB);    // 6 MB  [3072][1024]
  bf16* Wob   = (bf16*)(ws + 14 * MB);   // 2 MB
  bf16* QKVb  = (bf16*)(ws + 16 * MB);   // 24 MB [4096][3072] (V cols unused)
  bf16* VTb   = (bf16*)(ws + 40 * MB);   // 8 MB  [2048][2048]
  float* biasTab = (float*)(ws + 48 * MB);  // 16*4095*4 B

  // fused prep: X cvt + 4 weight cvts + bias table, one launch
  prep_kernel<<<8448, 256, 0, stream>>>(X, Wq, Wk, Wv, Wo, rel,
                                        Xb, Wqkvb, Wob, biasTab);

  // fused QKV projection; V cols written TRANSPOSED to VTb by epilogue
  gemm_bt<1, 4, 1><<<dim3(24, 32), 256, 0, stream>>>(Xb, Wqkvb, QKVb,
      VTb, /*vThr=*/2048,
      NROWS, 3 * D_, D_, /*colThr=*/1024, /*aQ=*/0.125f * LOG2E, /*a1=*/1.0f);

  attn_fwd<<<1024, 256, 0, stream>>>(QKVb, VTb, biasTab, rel, Xb /*Ob*/);

  // out projection: 64x128 tiles -> 512 blocks
  gemm_bt<0, 2, 0><<<dim3(8, 64), 256, 0, stream>>>(Xb, Wob, out,
      nullptr, 1 << 30,
      NROWS, D_, D_, /*colThr=*/0, 1.0f, 1.0f);
}